// Round 2
// baseline (8330.694 us; speedup 1.0000x reference)
//
#include <hip/hip_runtime.h>
#include <math.h>

#define N_NODES 50000
#define N_EDGES 500000
#define NB_CHUNK 12800

// ---------- bf16 helpers ----------
__device__ inline float b2f(unsigned short u) {
  union { unsigned int i; float f; } v; v.i = ((unsigned int)u) << 16; return v.f;
}
__device__ inline unsigned short f2b(float f) {
  union { float f; unsigned int i; } v; v.f = f;
  unsigned int x = v.i;
  return (unsigned short)((x + 0x7fffu + ((x >> 16) & 1u)) >> 16);
}
__device__ inline void stv(unsigned short* p, float v) { *p = f2b(v); }
__device__ inline void stv(float* p, float v) { *p = v; }
__device__ inline float ldf(unsigned short u) { return b2f(u); }
__device__ inline float ldf(float f) { return f; }

// ---------------- degree / CSR ----------------
__global__ void k_count(const int* __restrict__ src, const int* __restrict__ dst,
                        int* __restrict__ cnt, int* __restrict__ degall) {
  int e = blockIdx.x * blockDim.x + threadIdx.x;
  if (e < N_EDGES) {
    atomicAdd(&cnt[dst[e]], 1);
    atomicAdd(&degall[src[e]], 1);
    atomicAdd(&degall[dst[e]], 1);
  }
}

__global__ __launch_bounds__(1024) void k_scan(const int* __restrict__ cnt, int* __restrict__ ptr) {
  __shared__ int buf[1024];
  __shared__ int carry;
  if (threadIdx.x == 0) carry = 0;
  __syncthreads();
  for (int base = 0; base < N_NODES; base += 1024) {
    int i = base + threadIdx.x;
    int v = (i < N_NODES) ? cnt[i] : 0;
    buf[threadIdx.x] = v;
    __syncthreads();
    for (int off = 1; off < 1024; off <<= 1) {
      int tv = (threadIdx.x >= off) ? buf[threadIdx.x - off] : 0;
      __syncthreads();
      buf[threadIdx.x] += tv;
      __syncthreads();
    }
    if (i < N_NODES) ptr[i] = carry + buf[threadIdx.x] - v;
    int total = buf[1023];
    __syncthreads();
    if (threadIdx.x == 0) carry += total;
    __syncthreads();
  }
  if (threadIdx.x == 0) ptr[N_NODES] = carry;
}

__global__ void k_fill(const int* __restrict__ src, const int* __restrict__ dst,
                       const int* __restrict__ ptr, int* __restrict__ cnt, int* __restrict__ col) {
  int e = blockIdx.x * blockDim.x + threadIdx.x;
  if (e < N_EDGES) {
    int d = dst[e];
    int pos = atomicAdd(&cnt[d], 1);
    col[ptr[d] + pos] = src[e];
  }
}

__global__ void k_avglog(const int* __restrict__ degall, float* __restrict__ scal) {
  __shared__ float L[256];
  float s = 0.f;
  for (int n = blockIdx.x * blockDim.x + threadIdx.x; n < N_NODES; n += gridDim.x * blockDim.x)
    s += logf((float)degall[n] + 1.0f);
  L[threadIdx.x] = s;
  __syncthreads();
  for (int o = 128; o > 0; o >>= 1) {
    if (threadIdx.x < o) L[threadIdx.x] += L[threadIdx.x + o];
    __syncthreads();
  }
  if (threadIdx.x == 0) atomicAdd(&scal[0], L[0]);
}

__global__ void k_avg_fin(float* scal) {
  float avg = scal[0] / (float)N_NODES;
  scal[1] = avg;
  scal[2] = 1.0f / avg;
}

__global__ void k_scalars(const int* __restrict__ ptr, const float* __restrict__ scal,
                          float* __restrict__ a_arr, float* __restrict__ c_arr) {
  int n = blockIdx.x * blockDim.x + threadIdx.x;
  if (n < N_NODES) {
    int d = ptr[n + 1] - ptr[n];
    float degc = fmaxf((float)d, 1.f);
    float logd = logf(degc + 1.f);
    a_arr[n] = logd * scal[2];
    c_arr[n] = scal[1] / logd;
  }
}

__global__ void k_cast(const float* __restrict__ x, unsigned short* __restrict__ xb, int total) {
  int i = blockIdx.x * blockDim.x + threadIdx.x;
  if (i < total) xb[i] = f2b(x[i]);
}

// ---------------- fp32 GEMM (weights-only, small): C[M,Ncol] = A@B ----------------
__global__ __launch_bounds__(256) void k_gemm_f32(const float* __restrict__ A, const float* __restrict__ B,
                                                  float* __restrict__ C, int M, int Ncol, int K) {
  __shared__ float As[16][136];
  __shared__ float Bs[16][128];
  int tid = threadIdx.x;
  int row0 = blockIdx.y * 128, col0 = blockIdx.x * 128;
  int am = tid >> 1, ah = (tid & 1) * 8;
  int ty = tid >> 4, tx = tid & 15;
  float acc[8][8];
#pragma unroll
  for (int i = 0; i < 8; i++)
#pragma unroll
    for (int j = 0; j < 8; j++) acc[i][j] = 0.f;
  int arow = row0 + am;
  bool av = arow < M;
  const float* Ar = A + (size_t)arow * K;
  for (int k0 = 0; k0 < K; k0 += 16) {
    float4 a0 = make_float4(0, 0, 0, 0), a1 = make_float4(0, 0, 0, 0);
    if (av) {
      a0 = *(const float4*)(Ar + k0 + ah);
      a1 = *(const float4*)(Ar + k0 + ah + 4);
    }
    As[ah + 0][am] = a0.x; As[ah + 1][am] = a0.y; As[ah + 2][am] = a0.z; As[ah + 3][am] = a0.w;
    As[ah + 4][am] = a1.x; As[ah + 5][am] = a1.y; As[ah + 6][am] = a1.z; As[ah + 7][am] = a1.w;
#pragma unroll
    for (int i = 0; i < 2; i++) {
      int q = tid * 2 + i;
      int kk = q >> 5, j4 = (q & 31) * 4;
      int bc = col0 + j4;
      float4 b = make_float4(0, 0, 0, 0);
      if (bc < Ncol) b = *(const float4*)(B + (size_t)(k0 + kk) * Ncol + bc);
      *(float4*)(&Bs[kk][j4]) = b;
    }
    __syncthreads();
#pragma unroll
    for (int kk = 0; kk < 16; kk++) {
      float av8[8], bv8[8];
#pragma unroll
      for (int i = 0; i < 8; i++) av8[i] = As[kk][ty * 8 + i];
#pragma unroll
      for (int j = 0; j < 8; j++) bv8[j] = Bs[kk][tx * 8 + j];
#pragma unroll
      for (int i = 0; i < 8; i++)
#pragma unroll
        for (int j = 0; j < 8; j++) acc[i][j] = fmaf(av8[i], bv8[j], acc[i][j]);
    }
    __syncthreads();
  }
#pragma unroll
  for (int i = 0; i < 8; i++) {
    int r = row0 + ty * 8 + i;
    if (r < M) {
#pragma unroll
      for (int j = 0; j < 8; j++) {
        int c = col0 + tx * 8 + j;
        if (c < Ncol) C[(size_t)r * Ncol + c] = acc[i][j];
      }
    }
  }
}

// ---------------- bf16-A GEMM: C_bf16[M,Ncol] = A_bf16[M,K] @ B_f32[K,Ncol] (+bias) ----------------
__global__ __launch_bounds__(256) void k_gemm_bf(const unsigned short* __restrict__ A, const float* __restrict__ B,
                                                 unsigned short* __restrict__ C, const float* __restrict__ bias,
                                                 int M, int Ncol, int K) {
  __shared__ float As[16][136];
  __shared__ float Bs[16][128];
  int tid = threadIdx.x;
  int row0 = blockIdx.y * 128, col0 = blockIdx.x * 128;
  int am = tid >> 1, ah = (tid & 1) * 8;
  int ty = tid >> 4, tx = tid & 15;
  float acc[8][8];
#pragma unroll
  for (int i = 0; i < 8; i++)
#pragma unroll
    for (int j = 0; j < 8; j++) acc[i][j] = 0.f;
  int arow = row0 + am;
  bool av = arow < M;
  const unsigned short* Ar = A + (size_t)arow * K;
  for (int k0 = 0; k0 < K; k0 += 16) {
    uint4 a = make_uint4(0, 0, 0, 0);
    if (av) a = *(const uint4*)(Ar + k0 + ah);  // 8 bf16
    As[ah + 0][am] = b2f((unsigned short)(a.x & 0xffff));
    As[ah + 1][am] = b2f((unsigned short)(a.x >> 16));
    As[ah + 2][am] = b2f((unsigned short)(a.y & 0xffff));
    As[ah + 3][am] = b2f((unsigned short)(a.y >> 16));
    As[ah + 4][am] = b2f((unsigned short)(a.z & 0xffff));
    As[ah + 5][am] = b2f((unsigned short)(a.z >> 16));
    As[ah + 6][am] = b2f((unsigned short)(a.w & 0xffff));
    As[ah + 7][am] = b2f((unsigned short)(a.w >> 16));
#pragma unroll
    for (int i = 0; i < 2; i++) {
      int q = tid * 2 + i;
      int kk = q >> 5, j4 = (q & 31) * 4;
      int bc = col0 + j4;
      float4 b = make_float4(0, 0, 0, 0);
      if (bc < Ncol) b = *(const float4*)(B + (size_t)(k0 + kk) * Ncol + bc);
      *(float4*)(&Bs[kk][j4]) = b;
    }
    __syncthreads();
#pragma unroll
    for (int kk = 0; kk < 16; kk++) {
      float av8[8], bv8[8];
#pragma unroll
      for (int i = 0; i < 8; i++) av8[i] = As[kk][ty * 8 + i];
#pragma unroll
      for (int j = 0; j < 8; j++) bv8[j] = Bs[kk][tx * 8 + j];
#pragma unroll
      for (int i = 0; i < 8; i++)
#pragma unroll
        for (int j = 0; j < 8; j++) acc[i][j] = fmaf(av8[i], bv8[j], acc[i][j]);
    }
    __syncthreads();
  }
#pragma unroll
  for (int i = 0; i < 8; i++) {
    int r = row0 + ty * 8 + i;
    if (r < M) {
#pragma unroll
      for (int j = 0; j < 8; j++) {
        int c = col0 + tx * 8 + j;
        if (c < Ncol) C[(size_t)r * Ncol + c] = f2b(acc[i][j] + (bias ? bias[c] : 0.f));
      }
    }
  }
}

// ---------------- edge aggregation over s only, combined with t ----------------
// m_e = t[n] + s[src]; sum/var are t-shifted, min/max are t+min(s)/t+max(s).
template <int F>
__global__ __launch_bounds__(256) void k_edge_agg(const unsigned short* __restrict__ t,
                                                  const unsigned short* __restrict__ s,
                                                  const int* __restrict__ ptr, const int* __restrict__ col,
                                                  unsigned short* __restrict__ aggc, int n0, int nchunk) {
  constexpr int R = F / 64;
  int idx = (blockIdx.x * blockDim.x + threadIdx.x) >> 6;
  int lane = threadIdx.x & 63;
  if (idx >= nchunk) return;
  int n = n0 + idx;
  if (n >= N_NODES) return;
  float S1[R], S2[R], mn[R], mx[R];
#pragma unroll
  for (int r = 0; r < R; r++) {
    S1[r] = 0.f; S2[r] = 0.f;
    mn[r] = 3.4e38f; mx[r] = -3.4e38f;
  }
  int e0 = ptr[n], e1 = ptr[n + 1];
  for (int e = e0; e < e1; ++e) {
    int sidx = col[e];
    const unsigned short* srow = s + (size_t)sidx * F;
#pragma unroll
    for (int r = 0; r < R; r++) {
      float v = b2f(srow[lane + 64 * r]);
      S1[r] += v;
      S2[r] += v * v;
      mn[r] = fminf(mn[r], v);
      mx[r] = fmaxf(mx[r], v);
    }
  }
  int d = e1 - e0;
#pragma unroll
  for (int r = 0; r < R; r++) {
    float mean, sd, lo, hi;
    if (d > 0) {
      float inv = 1.f / (float)d;
      float ms = S1[r] * inv;
      float var = fmaxf(S2[r] * inv - ms * ms, 0.f);
      sd = sqrtf(var + 1e-5f);
      float tv = b2f(t[(size_t)n * F + lane + 64 * r]);
      mean = tv + ms;
      lo = tv + mn[r];
      hi = tv + mx[r];
    } else {
      mean = 0.f; lo = 0.f; hi = 0.f;
      sd = sqrtf(1e-5f);
    }
    size_t base = (size_t)idx * 4 * F + lane + 64 * r;
    aggc[base] = f2b(mean);
    aggc[base + F] = f2b(lo);
    aggc[base + 2 * F] = f2b(hi);
    aggc[base + 3 * F] = f2b(sd);
  }
}

// ---------------- post GEMM: A on-the-fly from [x | agg | a*agg | c*agg], chunked rows ----------------
template <int F, typename To>
__global__ __launch_bounds__(256) void k_post_gemm(const unsigned short* __restrict__ X,
                                                   const unsigned short* __restrict__ aggc,
                                                   const float* __restrict__ a_arr, const float* __restrict__ c_arr,
                                                   const float* __restrict__ B, const float* __restrict__ bias,
                                                   To* __restrict__ C, int n0, int nchunk, int Ncol) {
  constexpr int K = 13 * F;
  __shared__ float As[16][136];
  __shared__ float Bs[16][128];
  int tid = threadIdx.x;
  int row0 = blockIdx.y * 128, col0 = blockIdx.x * 128;
  int am = tid >> 1, ah = (tid & 1) * 8;
  int ty = tid >> 4, tx = tid & 15;
  float acc[8][8];
#pragma unroll
  for (int i = 0; i < 8; i++)
#pragma unroll
    for (int j = 0; j < 8; j++) acc[i][j] = 0.f;
  int lrow = row0 + am;
  int grow = n0 + lrow;
  bool av = (lrow < nchunk) && (grow < N_NODES);
  const unsigned short* xr = X + (size_t)grow * F;
  const unsigned short* gr = aggc + (size_t)lrow * 4 * F;
  float an = av ? a_arr[grow] : 0.f;
  float cn = av ? c_arr[grow] : 0.f;
  for (int k0 = 0; k0 < K; k0 += 16) {
#pragma unroll
    for (int h = 0; h < 2; h++) {
      int kg = k0 + ah + h * 4;
      float e0 = 0.f, e1 = 0.f, e2 = 0.f, e3 = 0.f;
      if (av) {
        ushort4 u;
        float sc = 1.f;
        if (kg < F) {
          u = *(const ushort4*)(xr + kg);
        } else if (kg < 5 * F) {
          u = *(const ushort4*)(gr + kg - F);
        } else if (kg < 9 * F) {
          u = *(const ushort4*)(gr + kg - 5 * F);
          sc = an;
        } else {
          u = *(const ushort4*)(gr + kg - 9 * F);
          sc = cn;
        }
        e0 = b2f(u.x) * sc; e1 = b2f(u.y) * sc; e2 = b2f(u.z) * sc; e3 = b2f(u.w) * sc;
      }
      As[ah + h * 4 + 0][am] = e0;
      As[ah + h * 4 + 1][am] = e1;
      As[ah + h * 4 + 2][am] = e2;
      As[ah + h * 4 + 3][am] = e3;
    }
#pragma unroll
    for (int i = 0; i < 2; i++) {
      int q = tid * 2 + i;
      int kk = q >> 5, j4 = (q & 31) * 4;
      int bc = col0 + j4;
      float4 b = make_float4(0, 0, 0, 0);
      if (bc < Ncol) b = *(const float4*)(B + (size_t)(k0 + kk) * Ncol + bc);
      *(float4*)(&Bs[kk][j4]) = b;
    }
    __syncthreads();
#pragma unroll
    for (int kk = 0; kk < 16; kk++) {
      float av8[8], bv8[8];
#pragma unroll
      for (int i = 0; i < 8; i++) av8[i] = As[kk][ty * 8 + i];
#pragma unroll
      for (int j = 0; j < 8; j++) bv8[j] = Bs[kk][tx * 8 + j];
#pragma unroll
      for (int i = 0; i < 8; i++)
#pragma unroll
        for (int j = 0; j < 8; j++) acc[i][j] = fmaf(av8[i], bv8[j], acc[i][j]);
    }
    __syncthreads();
  }
#pragma unroll
  for (int i = 0; i < 8; i++) {
    int lr = row0 + ty * 8 + i;
    int g = n0 + lr;
    if (lr < nchunk && g < N_NODES) {
#pragma unroll
      for (int j = 0; j < 8; j++) {
        int c = col0 + tx * 8 + j;
        if (c < Ncol) stv(&C[(size_t)g * Ncol + c], acc[i][j] + bias[c]);
      }
    }
  }
}

// ---------------- BN ----------------
template <int FO, typename Ti>
__global__ __launch_bounds__(256) void k_bn_stats(const Ti* __restrict__ o, float* __restrict__ gsum,
                                                  float* __restrict__ gsq) {
  constexpr int P = 256 / FO;
  int c = threadIdx.x % FO;
  int p = threadIdx.x / FO;
  float s1 = 0.f, s2 = 0.f;
  for (int n = blockIdx.x * P + p; n < N_NODES; n += gridDim.x * P) {
    float v = ldf(o[(size_t)n * FO + c]);
    s1 += v;
    s2 += v * v;
  }
  __shared__ float L1[256], L2[256];
  L1[threadIdx.x] = s1;
  L2[threadIdx.x] = s2;
  __syncthreads();
  if (p == 0) {
#pragma unroll
    for (int q = 1; q < P; q++) {
      s1 += L1[q * FO + c];
      s2 += L2[q * FO + c];
    }
    atomicAdd(&gsum[c], s1);
    atomicAdd(&gsq[c], s2);
  }
}

__global__ void k_bn_fin(const float* bnsum, const float* bnsq, float* bnmean, float* bnrs, int FO) {
  int c = threadIdx.x;
  if (c < FO) {
    float mean = bnsum[c] / (float)N_NODES;
    float var = bnsq[c] / (float)N_NODES - mean * mean;
    bnmean[c] = mean;
    bnrs[c] = rsqrtf(var + 1e-5f);
  }
}

template <typename Ti>
__global__ void k_bn_elu(const Ti* __restrict__ o, const float* __restrict__ mean,
                         const float* __restrict__ rs, const float* __restrict__ gamma,
                         const float* __restrict__ beta, unsigned short* __restrict__ h,
                         float* __restrict__ bnout, int FO) {
  int idx = blockIdx.x * blockDim.x + threadIdx.x;
  if (idx < N_NODES * FO) {
    int c = idx % FO;
    float y = gamma[c] * (ldf(o[idx]) - mean[c]) * rs[c] + beta[c];
    if (bnout) bnout[idx] = y;
    h[idx] = f2b(y > 0.f ? y : expm1f(y));
  }
}

// ---------------- misc ----------------
__global__ void k_bcomb(const float* __restrict__ bpost, const float* __restrict__ Wlin,
                        const float* __restrict__ blin, float* __restrict__ bcomb, int FO) {
  int j = threadIdx.x;
  if (j < FO) {
    float acc = blin[j];
    for (int k = 0; k < FO; k++) acc += bpost[k] * Wlin[k * FO + j];
    bcomb[j] = acc;
  }
}

__global__ void k_add(const unsigned short* __restrict__ a, const unsigned short* __restrict__ b,
                      unsigned short* __restrict__ c) {
  int idx = blockIdx.x * blockDim.x + threadIdx.x;
  if (idx < N_NODES * 128) c[idx] = f2b(b2f(a[idx]) + b2f(b[idx]));
}

__global__ void k_logits(const unsigned short* __restrict__ h4, const float* __restrict__ Wc,
                         const float* __restrict__ bc, float* __restrict__ out) {
  int n = blockIdx.x * blockDim.x + threadIdx.x;
  if (n < N_NODES) {
    float acc0 = bc[0], acc1 = bc[1];
    const unsigned short* hr = h4 + (size_t)n * 64;
    for (int k = 0; k < 64; k++) {
      float v = b2f(hr[k]);
      acc0 += v * Wc[k * 2 + 0];
      acc1 += v * Wc[k * 2 + 1];
    }
    out[n * 2 + 0] = acc0;
    out[n * 2 + 1] = acc1;
  }
}

// ---------------- driver ----------------
struct WS {
  int *ptr, *col, *cnt, *degall;
  float *scal, *a_arr, *c_arr, *bnsum, *bnsq, *bnmean, *bnrs, *wcomb, *bcomb;
  unsigned short *xb, *h1, *h2, *h3, *t, *s, *aggc;
};

template <int F, typename To>
static void run_layer(const unsigned short* xin, To* o_ptr, float* bnout, unsigned short* hout,
                      const float* Wpre, const float* bpre, const float* Wpost, const float* bpost,
                      const float* Wlin, const float* blin, const float* gamma, const float* beta,
                      int FO, const WS& ws, hipStream_t stream) {
  const int N = N_NODES;
  // t = xin @ Wpre[:F] + bpre ; s = xin @ Wpre[F:]
  {
    dim3 g((F + 127) / 128, (N + 127) / 128);
    k_gemm_bf<<<g, 256, 0, stream>>>(xin, Wpre, ws.t, bpre, N, F, F);
    k_gemm_bf<<<g, 256, 0, stream>>>(xin, Wpre + (size_t)F * F, ws.s, nullptr, N, F, F);
  }
  // wcomb = Wpost @ Wlin ; bcomb = bpost @ Wlin + blin
  {
    dim3 g((FO + 127) / 128, (13 * F + 127) / 128);
    k_gemm_f32<<<g, 256, 0, stream>>>(Wpost, Wlin, ws.wcomb, 13 * F, FO, FO);
    k_bcomb<<<1, 256, 0, stream>>>(bpost, Wlin, blin, ws.bcomb, FO);
  }
  // chunked: edge aggregation -> post GEMM
  for (int c0 = 0; c0 < N; c0 += NB_CHUNK) {
    int nc = (N - c0 < NB_CHUNK) ? (N - c0) : NB_CHUNK;
    k_edge_agg<F><<<(nc * 64 + 255) / 256, 256, 0, stream>>>(ws.t, ws.s, ws.ptr, ws.col, ws.aggc, c0, nc);
    dim3 g((FO + 127) / 128, (nc + 127) / 128);
    k_post_gemm<F, To><<<g, 256, 0, stream>>>(xin, ws.aggc, ws.a_arr, ws.c_arr, ws.wcomb, ws.bcomb,
                                              o_ptr, c0, nc, FO);
  }
  // BN + ELU
  hipMemsetAsync(ws.bnsum, 0, 256 * sizeof(float), stream);
  hipMemsetAsync(ws.bnsq, 0, 256 * sizeof(float), stream);
  if (FO == 64)
    k_bn_stats<64, To><<<128, 256, 0, stream>>>(o_ptr, ws.bnsum, ws.bnsq);
  else if (FO == 128)
    k_bn_stats<128, To><<<128, 256, 0, stream>>>(o_ptr, ws.bnsum, ws.bnsq);
  else
    k_bn_stats<256, To><<<128, 256, 0, stream>>>(o_ptr, ws.bnsum, ws.bnsq);
  k_bn_fin<<<1, 256, 0, stream>>>(ws.bnsum, ws.bnsq, ws.bnmean, ws.bnrs, FO);
  int total = N_NODES * FO;
  k_bn_elu<To><<<(total + 255) / 256, 256, 0, stream>>>(o_ptr, ws.bnmean, ws.bnrs, gamma, beta, hout, bnout, FO);
}

extern "C" void kernel_launch(void* const* d_in, const int* in_sizes, int n_in,
                              void* d_out, int out_size, void* d_ws, size_t ws_size,
                              hipStream_t stream) {
  const int N = N_NODES, E = N_EDGES;
  const float* x = (const float*)d_in[0];
  const int* ei = (const int*)d_in[1];
  const int* src = ei;
  const int* dst = ei + E;
  const float *Wpre[4], *bpre[4], *Wpost[4], *bpost[4], *Wlin[4], *blin[4], *gamma[4], *beta[4];
  for (int i = 0; i < 4; i++) {
    const int b = 2 + i * 8;
    Wpre[i] = (const float*)d_in[b + 0];
    bpre[i] = (const float*)d_in[b + 1];
    Wpost[i] = (const float*)d_in[b + 2];
    bpost[i] = (const float*)d_in[b + 3];
    Wlin[i] = (const float*)d_in[b + 4];
    blin[i] = (const float*)d_in[b + 5];
    gamma[i] = (const float*)d_in[b + 6];
    beta[i] = (const float*)d_in[b + 7];
  }
  const float* Wc = (const float*)d_in[34];
  const float* bcv = (const float*)d_in[35];

  // ----- workspace layout (~146 MB) -----
  char* w = (char*)d_ws;
  size_t off = 0;
  auto alloc = [&](size_t bytes) -> void* {
    void* p = (void*)(w + off);
    off = (off + bytes + 255) & ~(size_t)255;
    return p;
  };
  WS ws;
  ws.ptr = (int*)alloc((N + 1) * sizeof(int));
  ws.col = (int*)alloc((size_t)E * sizeof(int));
  ws.cnt = (int*)alloc((size_t)N * sizeof(int));
  ws.degall = (int*)alloc((size_t)N * sizeof(int));
  ws.scal = (float*)alloc(16 * sizeof(float));
  ws.a_arr = (float*)alloc((size_t)N * sizeof(float));
  ws.c_arr = (float*)alloc((size_t)N * sizeof(float));
  ws.bnsum = (float*)alloc(256 * sizeof(float));
  ws.bnsq = (float*)alloc(256 * sizeof(float));
  ws.bnmean = (float*)alloc(256 * sizeof(float));
  ws.bnrs = (float*)alloc(256 * sizeof(float));
  ws.wcomb = (float*)alloc((size_t)13 * 256 * 128 * sizeof(float));
  ws.bcomb = (float*)alloc(256 * sizeof(float));
  ws.xb = (unsigned short*)alloc((size_t)N * 128 * sizeof(unsigned short));
  ws.h1 = (unsigned short*)alloc((size_t)N * 128 * sizeof(unsigned short));
  ws.h2 = (unsigned short*)alloc((size_t)N * 256 * sizeof(unsigned short));
  ws.h3 = (unsigned short*)alloc((size_t)N * 128 * sizeof(unsigned short));
  ws.t = (unsigned short*)alloc((size_t)N * 256 * sizeof(unsigned short));
  ws.s = (unsigned short*)alloc((size_t)N * 256 * sizeof(unsigned short));
  ws.aggc = (unsigned short*)alloc((size_t)NB_CHUNK * 1024 * sizeof(unsigned short));
  unsigned short* h4 = ws.xb;  // alias: x dead after layer 1; h4 is [N,64]

  float* outp = (float*)d_out;
  float* logits = outp;              // [N,2]
  float* p4 = outp + (size_t)N * 2;  // [N,64]
  float* b4 = p4 + (size_t)N * 64;   // [N,64]
  // pre-BN scratch for layers 1-3 lives in the p4/b4 area of d_out (25.6 MB),
  // fully overwritten by layer 4 afterwards.
  unsigned short* o_scratch = (unsigned short*)p4;

  // ----- degree / CSR / scalars -----
  hipMemsetAsync(ws.cnt, 0, N * sizeof(int), stream);
  hipMemsetAsync(ws.degall, 0, N * sizeof(int), stream);
  hipMemsetAsync(ws.scal, 0, 16 * sizeof(float), stream);
  k_count<<<(E + 255) / 256, 256, 0, stream>>>(src, dst, ws.cnt, ws.degall);
  k_scan<<<1, 1024, 0, stream>>>(ws.cnt, ws.ptr);
  hipMemsetAsync(ws.cnt, 0, N * sizeof(int), stream);
  k_fill<<<(E + 255) / 256, 256, 0, stream>>>(src, dst, ws.ptr, ws.cnt, ws.col);
  k_avglog<<<64, 256, 0, stream>>>(ws.degall, ws.scal);
  k_avg_fin<<<1, 1, 0, stream>>>(ws.scal);
  k_scalars<<<(N + 255) / 256, 256, 0, stream>>>(ws.ptr, ws.scal, ws.a_arr, ws.c_arr);
  k_cast<<<(N * 128 + 255) / 256, 256, 0, stream>>>(x, ws.xb, N * 128);

  run_layer<128, unsigned short>(ws.xb, o_scratch, nullptr, ws.h1,
                                 Wpre[0], bpre[0], Wpost[0], bpost[0], Wlin[0], blin[0], gamma[0], beta[0],
                                 128, ws, stream);
  run_layer<128, unsigned short>(ws.h1, o_scratch, nullptr, ws.h2,
                                 Wpre[1], bpre[1], Wpost[1], bpost[1], Wlin[1], blin[1], gamma[1], beta[1],
                                 256, ws, stream);
  run_layer<256, unsigned short>(ws.h2, o_scratch, nullptr, ws.h3,
                                 Wpre[2], bpre[2], Wpost[2], bpost[2], Wlin[2], blin[2], gamma[2], beta[2],
                                 128, ws, stream);
  k_add<<<((N * 128) + 255) / 256, 256, 0, stream>>>(ws.h1, ws.h3, ws.h3);  // x4 = h1 + h3 in place
  run_layer<128, float>(ws.h3, p4, b4, h4,
                        Wpre[3], bpre[3], Wpost[3], bpost[3], Wlin[3], blin[3], gamma[3], beta[3],
                        64, ws, stream);
  k_logits<<<(N + 255) / 256, 256, 0, stream>>>(h4, Wc, bcv, logits);
  (void)in_sizes; (void)n_in; (void)out_size; (void)ws_size;
}

// Round 3
// 1786.880 us; speedup vs baseline: 4.6621x; 4.6621x over previous
//
#include <hip/hip_runtime.h>
#include <math.h>

#define N_NODES 50000
#define N_EDGES 500000

using bf16x8 = __attribute__((ext_vector_type(8))) short;
using f32x4  = __attribute__((ext_vector_type(4))) float;

// ---------- bf16 helpers ----------
__device__ inline float b2f(unsigned short u) {
  union { unsigned int i; float f; } v; v.i = ((unsigned int)u) << 16; return v.f;
}
__device__ inline unsigned short f2b(float f) {
  union { float f; unsigned int i; } v; v.f = f;
  unsigned int x = v.i;
  return (unsigned short)((x + 0x7fffu + ((x >> 16) & 1u)) >> 16);
}
__device__ inline void stv(unsigned short* p, float v) { *p = f2b(v); }
__device__ inline void stv(float* p, float v) { *p = v; }
__device__ inline float ldf(unsigned short u) { return b2f(u); }
__device__ inline float ldf(float f) { return f; }

// ---------------- degree / CSR ----------------
__global__ void k_count(const int* __restrict__ src, const int* __restrict__ dst,
                        int* __restrict__ cnt, int* __restrict__ degall) {
  int e = blockIdx.x * blockDim.x + threadIdx.x;
  if (e < N_EDGES) {
    atomicAdd(&cnt[dst[e]], 1);
    atomicAdd(&degall[src[e]], 1);
    atomicAdd(&degall[dst[e]], 1);
  }
}

__global__ __launch_bounds__(1024) void k_scan(const int* __restrict__ cnt, int* __restrict__ ptr) {
  __shared__ int buf[1024];
  __shared__ int carry;
  if (threadIdx.x == 0) carry = 0;
  __syncthreads();
  for (int base = 0; base < N_NODES; base += 1024) {
    int i = base + threadIdx.x;
    int v = (i < N_NODES) ? cnt[i] : 0;
    buf[threadIdx.x] = v;
    __syncthreads();
    for (int off = 1; off < 1024; off <<= 1) {
      int tv = (threadIdx.x >= off) ? buf[threadIdx.x - off] : 0;
      __syncthreads();
      buf[threadIdx.x] += tv;
      __syncthreads();
    }
    if (i < N_NODES) ptr[i] = carry + buf[threadIdx.x] - v;
    int total = buf[1023];
    __syncthreads();
    if (threadIdx.x == 0) carry += total;
    __syncthreads();
  }
  if (threadIdx.x == 0) ptr[N_NODES] = carry;
}

__global__ void k_fill(const int* __restrict__ src, const int* __restrict__ dst,
                       const int* __restrict__ ptr, int* __restrict__ cnt, int* __restrict__ col) {
  int e = blockIdx.x * blockDim.x + threadIdx.x;
  if (e < N_EDGES) {
    int d = dst[e];
    int pos = atomicAdd(&cnt[d], 1);
    col[ptr[d] + pos] = src[e];
  }
}

__global__ void k_avglog(const int* __restrict__ degall, float* __restrict__ scal) {
  __shared__ float L[256];
  float s = 0.f;
  for (int n = blockIdx.x * blockDim.x + threadIdx.x; n < N_NODES; n += gridDim.x * blockDim.x)
    s += logf((float)degall[n] + 1.0f);
  L[threadIdx.x] = s;
  __syncthreads();
  for (int o = 128; o > 0; o >>= 1) {
    if (threadIdx.x < o) L[threadIdx.x] += L[threadIdx.x + o];
    __syncthreads();
  }
  if (threadIdx.x == 0) atomicAdd(&scal[0], L[0]);
}

__global__ void k_avg_fin(float* scal) {
  float avg = scal[0] / (float)N_NODES;
  scal[1] = avg;
  scal[2] = 1.0f / avg;
}

__global__ void k_scalars(const int* __restrict__ ptr, const float* __restrict__ scal,
                          float* __restrict__ a_arr, float* __restrict__ c_arr) {
  int n = blockIdx.x * blockDim.x + threadIdx.x;
  if (n < N_NODES) {
    int d = ptr[n + 1] - ptr[n];
    float degc = fmaxf((float)d, 1.f);
    float logd = logf(degc + 1.f);
    a_arr[n] = logd * scal[2];
    c_arr[n] = scal[1] / logd;
  }
}

__global__ void k_cast(const float* __restrict__ x, unsigned short* __restrict__ xb, int total) {
  int i = blockIdx.x * blockDim.x + threadIdx.x;
  if (i < total) xb[i] = f2b(x[i]);
}

// transpose + cast: out[n*K + k] = bf16(in[(r0+k)*Ncol + n]), n<Ncol, k<K
__global__ void k_tcast(const float* __restrict__ in, unsigned short* __restrict__ out,
                        int K, int Ncol, int r0) {
  int i = blockIdx.x * blockDim.x + threadIdx.x;
  if (i < K * Ncol) {
    int n = i / K, k = i % K;
    out[i] = f2b(in[(size_t)(r0 + k) * Ncol + n]);
  }
}

// ---------------- fp32 GEMM (tiny, weights-only): C[M,Ncol] = A@B ----------------
__global__ __launch_bounds__(256) void k_gemm_f32(const float* __restrict__ A, const float* __restrict__ B,
                                                  float* __restrict__ C, int M, int Ncol, int K) {
  __shared__ float As[16][136];
  __shared__ float Bs[16][128];
  int tid = threadIdx.x;
  int row0 = blockIdx.y * 128, col0 = blockIdx.x * 128;
  int am = tid >> 1, ah = (tid & 1) * 8;
  int ty = tid >> 4, tx = tid & 15;
  float acc[8][8];
#pragma unroll
  for (int i = 0; i < 8; i++)
#pragma unroll
    for (int j = 0; j < 8; j++) acc[i][j] = 0.f;
  int arow = row0 + am;
  bool av = arow < M;
  const float* Ar = A + (size_t)arow * K;
  for (int k0 = 0; k0 < K; k0 += 16) {
    float4 a0 = make_float4(0, 0, 0, 0), a1 = make_float4(0, 0, 0, 0);
    if (av) {
      a0 = *(const float4*)(Ar + k0 + ah);
      a1 = *(const float4*)(Ar + k0 + ah + 4);
    }
    As[ah + 0][am] = a0.x; As[ah + 1][am] = a0.y; As[ah + 2][am] = a0.z; As[ah + 3][am] = a0.w;
    As[ah + 4][am] = a1.x; As[ah + 5][am] = a1.y; As[ah + 6][am] = a1.z; As[ah + 7][am] = a1.w;
#pragma unroll
    for (int i = 0; i < 2; i++) {
      int q = tid * 2 + i;
      int kk = q >> 5, j4 = (q & 31) * 4;
      int bc = col0 + j4;
      float4 b = make_float4(0, 0, 0, 0);
      if (bc < Ncol) b = *(const float4*)(B + (size_t)(k0 + kk) * Ncol + bc);
      *(float4*)(&Bs[kk][j4]) = b;
    }
    __syncthreads();
#pragma unroll
    for (int kk = 0; kk < 16; kk++) {
      float av8[8], bv8[8];
#pragma unroll
      for (int i = 0; i < 8; i++) av8[i] = As[kk][ty * 8 + i];
#pragma unroll
      for (int j = 0; j < 8; j++) bv8[j] = Bs[kk][tx * 8 + j];
#pragma unroll
      for (int i = 0; i < 8; i++)
#pragma unroll
        for (int j = 0; j < 8; j++) acc[i][j] = fmaf(av8[i], bv8[j], acc[i][j]);
    }
    __syncthreads();
  }
#pragma unroll
  for (int i = 0; i < 8; i++) {
    int r = row0 + ty * 8 + i;
    if (r < M) {
#pragma unroll
      for (int j = 0; j < 8; j++) {
        int c = col0 + tx * 8 + j;
        if (c < Ncol) C[(size_t)r * Ncol + c] = acc[i][j];
      }
    }
  }
}

// ---------------- MFMA bf16 GEMM (plain A, or 4-phase virtual post-A) ----------------
// C[n0+r, col] (r<M) = sum over phases of scale_ph(row) * (A_ph @ B_ph) + bias
// B given transposed bf16: BT[Ncol][KB]. POST phases: x@W1 + g@W2 + an*(g@W3) + cn*(g@W4).
template <int NTILE, bool POST, typename To>
__global__ __launch_bounds__(256) void k_mfma(
    const unsigned short* __restrict__ A0,   // POST ? X (global rows) : A plain (global rows)
    const unsigned short* __restrict__ G,    // POST: agg chunk, local rows, lda=4F
    const float* __restrict__ a_arr, const float* __restrict__ c_arr,
    const unsigned short* __restrict__ BT, int KB,
    const float* __restrict__ bias,
    To* __restrict__ C, int n0, int M, int Ncol, int Fdim) {
  constexpr int MF = (NTILE == 128) ? 4 : 2;
  constexpr int NF = 4;
  constexpr int PK = 56;  // pad: 112B rows -> 16B-aligned frags, ~2-way (free) bank pattern
  __shared__ unsigned short As[128][PK];
  __shared__ unsigned short Bs[NTILE][PK];
  const int tid = threadIdx.x;
  const int lane = tid & 63;
  const int wid = tid >> 6;
  const int wr = (NTILE == 128) ? (wid >> 1) : wid;
  const int wc = (NTILE == 128) ? (wid & 1) : 0;
  const int row0 = blockIdx.y * 128;
  const int col0 = blockIdx.x * NTILE;
  const int l15 = lane & 15;
  const int lk8 = (lane >> 4) * 8;
  const int rfb = wr * MF * 16, cfb = wc * NF * 16;
  const int akc = (tid & 3) * 8;
  const int arow = tid >> 2;

  f32x4 master[MF][NF];
  f32x4 acc[MF][NF];
#pragma unroll
  for (int m = 0; m < MF; m++)
#pragma unroll
    for (int n = 0; n < NF; n++) master[m][n] = (f32x4){0.f, 0.f, 0.f, 0.f};

  const int nph = POST ? 4 : 1;
  for (int ph = 0; ph < nph; ++ph) {
    const unsigned short* Ap;
    int lda, kext, kbase, rowbase, rlim, smode;
    if constexpr (POST) {
      if (ph == 0)      { Ap = A0; lda = Fdim;     kext = Fdim;     kbase = 0;        rowbase = n0; rlim = n0 + M; smode = 0; }
      else if (ph == 1) { Ap = G;  lda = 4 * Fdim; kext = 4 * Fdim; kbase = Fdim;     rowbase = 0;  rlim = M;      smode = 0; }
      else if (ph == 2) { Ap = G;  lda = 4 * Fdim; kext = 4 * Fdim; kbase = 5 * Fdim; rowbase = 0;  rlim = M;      smode = 1; }
      else              { Ap = G;  lda = 4 * Fdim; kext = 4 * Fdim; kbase = 9 * Fdim; rowbase = 0;  rlim = M;      smode = 2; }
    } else {
      Ap = A0; lda = KB; kext = KB; kbase = 0; rowbase = n0; rlim = n0 + M; smode = 0;
    }
#pragma unroll
    for (int m = 0; m < MF; m++)
#pragma unroll
      for (int n = 0; n < NF; n++) acc[m][n] = (f32x4){0.f, 0.f, 0.f, 0.f};

    for (int k0 = 0; k0 < kext; k0 += 32) {
      // stage A tile 128x32 (pure copy)
#pragma unroll
      for (int p = 0; p < 2; p++) {
        int r = arow + 64 * p;
        int gr = rowbase + row0 + r;
        uint4 v = make_uint4(0u, 0u, 0u, 0u);
        if (gr < rlim) v = *(const uint4*)(Ap + (size_t)gr * lda + k0 + akc);
        *(uint4*)&As[r][akc] = v;
      }
      // stage B tile NTILEx32
#pragma unroll
      for (int p = 0; p < NTILE / 64; p++) {
        int nn = arow + 64 * p;
        uint4 v = *(const uint4*)(BT + (size_t)(col0 + nn) * KB + kbase + k0 + akc);
        *(uint4*)&Bs[nn][akc] = v;
      }
      __syncthreads();
      bf16x8 af[MF], bfr[NF];
#pragma unroll
      for (int m = 0; m < MF; m++) af[m] = *(const bf16x8*)&As[rfb + m * 16 + l15][lk8];
#pragma unroll
      for (int n = 0; n < NF; n++) bfr[n] = *(const bf16x8*)&Bs[cfb + n * 16 + l15][lk8];
#pragma unroll
      for (int m = 0; m < MF; m++)
#pragma unroll
        for (int n = 0; n < NF; n++)
          acc[m][n] = __builtin_amdgcn_mfma_f32_16x16x32_bf16(af[m], bfr[n], acc[m][n], 0, 0, 0);
      __syncthreads();
    }
    // fold phase into master (per-row scale via C/D row mapping: row=(lane>>4)*4+j)
    if (smode == 0) {
#pragma unroll
      for (int m = 0; m < MF; m++)
#pragma unroll
        for (int n = 0; n < NF; n++) master[m][n] += acc[m][n];
    } else {
      const float* sarr = (smode == 1) ? a_arr : c_arr;
#pragma unroll
      for (int m = 0; m < MF; m++) {
        f32x4 sv;
#pragma unroll
        for (int j = 0; j < 4; j++) {
          int grow = n0 + row0 + rfb + m * 16 + (lane >> 4) * 4 + j;
          sv[j] = (grow < N_NODES) ? sarr[grow] : 0.f;
        }
#pragma unroll
        for (int n = 0; n < NF; n++) master[m][n] += sv * acc[m][n];
      }
    }
  }
  // epilogue
#pragma unroll
  for (int n = 0; n < NF; n++) {
    int col = col0 + cfb + n * 16 + l15;
    float bv = bias ? bias[col] : 0.f;
#pragma unroll
    for (int m = 0; m < MF; m++) {
#pragma unroll
      for (int j = 0; j < 4; j++) {
        int r = row0 + rfb + m * 16 + (lane >> 4) * 4 + j;
        if (r < M) stv(&C[(size_t)(n0 + r) * Ncol + col], master[m][n][j] + bv);
      }
    }
  }
}

// ---------------- edge aggregation over s only, combined with t ----------------
template <int F>
__global__ __launch_bounds__(256) void k_edge_agg(const unsigned short* __restrict__ t,
                                                  const unsigned short* __restrict__ s,
                                                  const int* __restrict__ ptr, const int* __restrict__ col,
                                                  unsigned short* __restrict__ aggc, int n0, int nchunk) {
  constexpr int R = F / 64;
  int idx = (blockIdx.x * blockDim.x + threadIdx.x) >> 6;
  int lane = threadIdx.x & 63;
  if (idx >= nchunk) return;
  int n = n0 + idx;
  if (n >= N_NODES) return;
  float S1[R], S2[R], mn[R], mx[R];
#pragma unroll
  for (int r = 0; r < R; r++) {
    S1[r] = 0.f; S2[r] = 0.f;
    mn[r] = 3.4e38f; mx[r] = -3.4e38f;
  }
  int e0 = ptr[n], e1 = ptr[n + 1];
  for (int e = e0; e < e1; ++e) {
    int sidx = col[e];
    const unsigned short* srow = s + (size_t)sidx * F;
#pragma unroll
    for (int r = 0; r < R; r++) {
      float v = b2f(srow[lane + 64 * r]);
      S1[r] += v;
      S2[r] += v * v;
      mn[r] = fminf(mn[r], v);
      mx[r] = fmaxf(mx[r], v);
    }
  }
  int d = e1 - e0;
#pragma unroll
  for (int r = 0; r < R; r++) {
    float mean, sd, lo, hi;
    if (d > 0) {
      float inv = 1.f / (float)d;
      float ms = S1[r] * inv;
      float var = fmaxf(S2[r] * inv - ms * ms, 0.f);
      sd = sqrtf(var + 1e-5f);
      float tv = b2f(t[(size_t)n * F + lane + 64 * r]);
      mean = tv + ms;
      lo = tv + mn[r];
      hi = tv + mx[r];
    } else {
      mean = 0.f; lo = 0.f; hi = 0.f;
      sd = sqrtf(1e-5f);
    }
    size_t base = (size_t)idx * 4 * F + lane + 64 * r;
    aggc[base] = f2b(mean);
    aggc[base + F] = f2b(lo);
    aggc[base + 2 * F] = f2b(hi);
    aggc[base + 3 * F] = f2b(sd);
  }
}

// ---------------- BN ----------------
template <int FO, typename Ti>
__global__ __launch_bounds__(256) void k_bn_stats(const Ti* __restrict__ o, float* __restrict__ gsum,
                                                  float* __restrict__ gsq) {
  constexpr int P = 256 / FO;
  int c = threadIdx.x % FO;
  int p = threadIdx.x / FO;
  float s1 = 0.f, s2 = 0.f;
  for (int n = blockIdx.x * P + p; n < N_NODES; n += gridDim.x * P) {
    float v = ldf(o[(size_t)n * FO + c]);
    s1 += v;
    s2 += v * v;
  }
  __shared__ float L1[256], L2[256];
  L1[threadIdx.x] = s1;
  L2[threadIdx.x] = s2;
  __syncthreads();
  if (p == 0) {
#pragma unroll
    for (int q = 1; q < P; q++) {
      s1 += L1[q * FO + c];
      s2 += L2[q * FO + c];
    }
    atomicAdd(&gsum[c], s1);
    atomicAdd(&gsq[c], s2);
  }
}

__global__ void k_bn_fin(const float* bnsum, const float* bnsq, float* bnmean, float* bnrs, int FO) {
  int c = threadIdx.x;
  if (c < FO) {
    float mean = bnsum[c] / (float)N_NODES;
    float var = bnsq[c] / (float)N_NODES - mean * mean;
    bnmean[c] = mean;
    bnrs[c] = rsqrtf(var + 1e-5f);
  }
}

template <typename Ti>
__global__ void k_bn_elu(const Ti* __restrict__ o, const float* __restrict__ mean,
                         const float* __restrict__ rs, const float* __restrict__ gamma,
                         const float* __restrict__ beta, unsigned short* __restrict__ h,
                         float* __restrict__ bnout, int FO) {
  int idx = blockIdx.x * blockDim.x + threadIdx.x;
  if (idx < N_NODES * FO) {
    int c = idx % FO;
    float y = gamma[c] * (ldf(o[idx]) - mean[c]) * rs[c] + beta[c];
    if (bnout) bnout[idx] = y;
    h[idx] = f2b(y > 0.f ? y : expm1f(y));
  }
}

// ---------------- misc ----------------
__global__ void k_bcomb(const float* __restrict__ bpost, const float* __restrict__ Wlin,
                        const float* __restrict__ blin, float* __restrict__ bcomb, int FO) {
  int j = threadIdx.x;
  if (j < FO) {
    float acc = blin[j];
    for (int k = 0; k < FO; k++) acc += bpost[k] * Wlin[k * FO + j];
    bcomb[j] = acc;
  }
}

__global__ void k_add(const unsigned short* __restrict__ a, const unsigned short* __restrict__ b,
                      unsigned short* __restrict__ c) {
  int idx = blockIdx.x * blockDim.x + threadIdx.x;
  if (idx < N_NODES * 128) c[idx] = f2b(b2f(a[idx]) + b2f(b[idx]));
}

__global__ void k_logits(const unsigned short* __restrict__ h4, const float* __restrict__ Wc,
                         const float* __restrict__ bc, float* __restrict__ out) {
  int n = blockIdx.x * blockDim.x + threadIdx.x;
  if (n < N_NODES) {
    float acc0 = bc[0], acc1 = bc[1];
    const unsigned short* hr = h4 + (size_t)n * 64;
    for (int k = 0; k < 64; k++) {
      float v = b2f(hr[k]);
      acc0 += v * Wc[k * 2 + 0];
      acc1 += v * Wc[k * 2 + 1];
    }
    out[n * 2 + 0] = acc0;
    out[n * 2 + 1] = acc1;
  }
}

// ---------------- driver ----------------
struct WS {
  int *ptr, *col, *cnt, *degall;
  float *scal, *a_arr, *c_arr, *bnsum, *bnsq, *bnmean, *bnrs, *wcomb, *bcomb;
  unsigned short *wcombT, *wpT1, *wpT2;
  unsigned short *xb, *h1, *h2, *h3, *t, *s, *aggc;
  int NB;
};

template <int F, typename To>
static void run_layer(const unsigned short* xin, To* o_ptr, float* bnout, unsigned short* hout,
                      const float* Wpre, const float* bpre, const float* Wpost, const float* bpost,
                      const float* Wlin, const float* blin, const float* gamma, const float* beta,
                      int FO, const WS& ws, hipStream_t stream) {
  const int N = N_NODES;
  const int K13 = 13 * F;
  // weight prep: wcomb = Wpost@Wlin (f32) -> wcombT bf16 [FO][13F]; WpreT slices bf16 [F][F]
  {
    dim3 g((FO + 127) / 128, (K13 + 127) / 128);
    k_gemm_f32<<<g, 256, 0, stream>>>(Wpost, Wlin, ws.wcomb, K13, FO, FO);
    k_bcomb<<<1, 256, 0, stream>>>(bpost, Wlin, blin, ws.bcomb, FO);
    k_tcast<<<(K13 * FO + 255) / 256, 256, 0, stream>>>(ws.wcomb, ws.wcombT, K13, FO, 0);
    k_tcast<<<(F * F + 255) / 256, 256, 0, stream>>>(Wpre, ws.wpT1, F, F, 0);
    k_tcast<<<(F * F + 255) / 256, 256, 0, stream>>>(Wpre, ws.wpT2, F, F, F);
  }
  // pre GEMMs: t = x@W1pre + bpre ; s = x@W2pre
  {
    dim3 g(F / 128, (N + 127) / 128);
    k_mfma<128, false, unsigned short><<<g, 256, 0, stream>>>(
        xin, nullptr, nullptr, nullptr, ws.wpT1, F, bpre, ws.t, 0, N, F, 0);
    k_mfma<128, false, unsigned short><<<g, 256, 0, stream>>>(
        xin, nullptr, nullptr, nullptr, ws.wpT2, F, nullptr, ws.s, 0, N, F, 0);
  }
  // chunked: edge aggregation -> post GEMM
  for (int c0 = 0; c0 < N; c0 += ws.NB) {
    int nc = (N - c0 < ws.NB) ? (N - c0) : ws.NB;
    k_edge_agg<F><<<(nc * 64 + 255) / 256, 256, 0, stream>>>(ws.t, ws.s, ws.ptr, ws.col, ws.aggc, c0, nc);
    if (FO == 64) {
      dim3 g(1, (nc + 127) / 128);
      k_mfma<64, true, To><<<g, 256, 0, stream>>>(xin, ws.aggc, ws.a_arr, ws.c_arr, ws.wcombT, K13,
                                                  ws.bcomb, o_ptr, c0, nc, FO, F);
    } else {
      dim3 g(FO / 128, (nc + 127) / 128);
      k_mfma<128, true, To><<<g, 256, 0, stream>>>(xin, ws.aggc, ws.a_arr, ws.c_arr, ws.wcombT, K13,
                                                   ws.bcomb, o_ptr, c0, nc, FO, F);
    }
  }
  // BN + ELU
  hipMemsetAsync(ws.bnsum, 0, 256 * sizeof(float), stream);
  hipMemsetAsync(ws.bnsq, 0, 256 * sizeof(float), stream);
  if (FO == 64)
    k_bn_stats<64, To><<<128, 256, 0, stream>>>(o_ptr, ws.bnsum, ws.bnsq);
  else if (FO == 128)
    k_bn_stats<128, To><<<128, 256, 0, stream>>>(o_ptr, ws.bnsum, ws.bnsq);
  else
    k_bn_stats<256, To><<<128, 256, 0, stream>>>(o_ptr, ws.bnsum, ws.bnsq);
  k_bn_fin<<<1, 256, 0, stream>>>(ws.bnsum, ws.bnsq, ws.bnmean, ws.bnrs, FO);
  int total = N_NODES * FO;
  k_bn_elu<To><<<(total + 255) / 256, 256, 0, stream>>>(o_ptr, ws.bnmean, ws.bnrs, gamma, beta, hout, bnout, FO);
}

extern "C" void kernel_launch(void* const* d_in, const int* in_sizes, int n_in,
                              void* d_out, int out_size, void* d_ws, size_t ws_size,
                              hipStream_t stream) {
  const int N = N_NODES, E = N_EDGES;
  const float* x = (const float*)d_in[0];
  const int* ei = (const int*)d_in[1];
  const int* src = ei;
  const int* dst = ei + E;
  const float *Wpre[4], *bpre[4], *Wpost[4], *bpost[4], *Wlin[4], *blin[4], *gamma[4], *beta[4];
  for (int i = 0; i < 4; i++) {
    const int b = 2 + i * 8;
    Wpre[i] = (const float*)d_in[b + 0];
    bpre[i] = (const float*)d_in[b + 1];
    Wpost[i] = (const float*)d_in[b + 2];
    bpost[i] = (const float*)d_in[b + 3];
    Wlin[i] = (const float*)d_in[b + 4];
    blin[i] = (const float*)d_in[b + 5];
    gamma[i] = (const float*)d_in[b + 6];
    beta[i] = (const float*)d_in[b + 7];
  }
  const float* Wc = (const float*)d_in[34];
  const float* bcv = (const float*)d_in[35];

  // ----- workspace layout (fixed ~121 MB, agg sized from what's left) -----
  char* w = (char*)d_ws;
  size_t off = 0;
  auto alloc = [&](size_t bytes) -> void* {
    void* p = (void*)(w + off);
    off = (off + bytes + 255) & ~(size_t)255;
    return p;
  };
  WS ws;
  ws.ptr = (int*)alloc((N + 1) * sizeof(int));
  ws.col = (int*)alloc((size_t)E * sizeof(int));
  ws.cnt = (int*)alloc((size_t)N * sizeof(int));
  ws.degall = (int*)alloc((size_t)N * sizeof(int));
  ws.scal = (float*)alloc(16 * sizeof(float));
  ws.a_arr = (float*)alloc((size_t)N * sizeof(float));
  ws.c_arr = (float*)alloc((size_t)N * sizeof(float));
  ws.bnsum = (float*)alloc(256 * sizeof(float));
  ws.bnsq = (float*)alloc(256 * sizeof(float));
  ws.bnmean = (float*)alloc(256 * sizeof(float));
  ws.bnrs = (float*)alloc(256 * sizeof(float));
  ws.wcomb = (float*)alloc((size_t)13 * 256 * 128 * sizeof(float));
  ws.bcomb = (float*)alloc(256 * sizeof(float));
  ws.wcombT = (unsigned short*)alloc((size_t)13 * 256 * 128 * sizeof(unsigned short));
  ws.wpT1 = (unsigned short*)alloc((size_t)256 * 256 * sizeof(unsigned short));
  ws.wpT2 = (unsigned short*)alloc((size_t)256 * 256 * sizeof(unsigned short));
  ws.xb = (unsigned short*)alloc((size_t)N * 128 * sizeof(unsigned short));
  ws.h1 = (unsigned short*)alloc((size_t)N * 128 * sizeof(unsigned short));
  ws.h2 = (unsigned short*)alloc((size_t)N * 256 * sizeof(unsigned short));
  ws.h3 = (unsigned short*)alloc((size_t)N * 128 * sizeof(unsigned short));
  ws.t = (unsigned short*)alloc((size_t)N * 256 * sizeof(unsigned short));
  ws.s = (unsigned short*)alloc((size_t)N * 256 * sizeof(unsigned short));
  // adaptive agg chunk: 4*F_max = 1024 bf16 per row
  size_t rem = (ws_size > off) ? (ws_size - off) : 0;
  size_t nbmax = rem / (1024 * sizeof(unsigned short));
  int NB = (nbmax >= (size_t)N) ? N : (int)(nbmax & ~(size_t)63);
  if (NB < 1600) NB = 1600;  // last resort
  ws.NB = NB;
  ws.aggc = (unsigned short*)alloc((size_t)NB * 1024 * sizeof(unsigned short));
  unsigned short* h4 = ws.xb;  // alias: x dead after layer 1; h4 is [N,64]

  float* outp = (float*)d_out;
  float* logits = outp;              // [N,2]
  float* p4 = outp + (size_t)N * 2;  // [N,64]
  float* b4 = p4 + (size_t)N * 64;   // [N,64]
  unsigned short* o_scratch = (unsigned short*)p4;  // pre-BN scratch, overwritten by layer 4

  // ----- degree / CSR / scalars -----
  hipMemsetAsync(ws.cnt, 0, N * sizeof(int), stream);
  hipMemsetAsync(ws.degall, 0, N * sizeof(int), stream);
  hipMemsetAsync(ws.scal, 0, 16 * sizeof(float), stream);
  k_count<<<(E + 255) / 256, 256, 0, stream>>>(src, dst, ws.cnt, ws.degall);
  k_scan<<<1, 1024, 0, stream>>>(ws.cnt, ws.ptr);
  hipMemsetAsync(ws.cnt, 0, N * sizeof(int), stream);
  k_fill<<<(E + 255) / 256, 256, 0, stream>>>(src, dst, ws.ptr, ws.cnt, ws.col);
  k_avglog<<<64, 256, 0, stream>>>(ws.degall, ws.scal);
  k_avg_fin<<<1, 1, 0, stream>>>(ws.scal);
  k_scalars<<<(N + 255) / 256, 256, 0, stream>>>(ws.ptr, ws.scal, ws.a_arr, ws.c_arr);
  k_cast<<<(N * 128 + 255) / 256, 256, 0, stream>>>(x, ws.xb, N * 128);

  run_layer<128, unsigned short>(ws.xb, o_scratch, nullptr, ws.h1,
                                 Wpre[0], bpre[0], Wpost[0], bpost[0], Wlin[0], blin[0], gamma[0], beta[0],
                                 128, ws, stream);
  run_layer<128, unsigned short>(ws.h1, o_scratch, nullptr, ws.h2,
                                 Wpre[1], bpre[1], Wpost[1], bpost[1], Wlin[1], blin[1], gamma[1], beta[1],
                                 256, ws, stream);
  run_layer<256, unsigned short>(ws.h2, o_scratch, nullptr, ws.h3,
                                 Wpre[2], bpre[2], Wpost[2], bpost[2], Wlin[2], blin[2], gamma[2], beta[2],
                                 128, ws, stream);
  k_add<<<((N * 128) + 255) / 256, 256, 0, stream>>>(ws.h1, ws.h3, ws.h3);  // x4 = h1 + h3 in place
  run_layer<128, float>(ws.h3, p4, b4, h4,
                        Wpre[3], bpre[3], Wpost[3], bpost[3], Wlin[3], blin[3], gamma[3], beta[3],
                        64, ws, stream);
  k_logits<<<(N + 255) / 256, 256, 0, stream>>>(h4, Wc, bcv, logits);
  (void)in_sizes; (void)n_in; (void)out_size; (void)ws_size;
}